// Round 6
// baseline (138.251 us; speedup 1.0000x reference)
//
#include <hip/hip_runtime.h>

typedef unsigned short u16;
typedef __attribute__((ext_vector_type(8))) short short8;
typedef __attribute__((ext_vector_type(4))) float f32x4;

// ---------------- helpers ----------------

__device__ __forceinline__ u16 f2bf(float f) {
    unsigned u = __float_as_uint(f);
    u += 0x7fffu + ((u >> 16) & 1u);   // round-to-nearest-even
    return (u16)(u >> 16);
}

// async global->LDS 16B copy; per-lane dst == wave-uniform base + lane*16.
__device__ __forceinline__ void lds_cp16(const u16* g, u16* l) {
#if defined(__has_builtin) && __has_builtin(__builtin_amdgcn_global_load_lds)
    __builtin_amdgcn_global_load_lds(
        (const __attribute__((address_space(1))) void*)g,
        (__attribute__((address_space(3))) void*)l, 16, 0, 0);
#else
    *(uint4*)l = *(const uint4*)g;
#endif
}

// raw workgroup barrier with compiler memory fences (no vmcnt drain!)
__device__ __forceinline__ void bar() {
    asm volatile("" ::: "memory");
    __builtin_amdgcn_s_barrier();
    asm volatile("" ::: "memory");
}

// ---------------- shared GEMM core (prefetch double-buffered, 2-phase) ----------------
// Used by k_scores / k_pv (unchanged this round).
template <bool ROWSUM>
__device__ __forceinline__ void gemm_core(const u16* __restrict__ Ag, int lda,
                                          const u16* __restrict__ Bg, int ldb,
                                          int ksteps, u16* Alds, u16* Blds,
                                          f32x4 (&acc)[4][4], f32x4* accL) {
    const int t = threadIdx.x;
    const int lane = t & 63;
    const int w = t >> 6;
    const int wr = (w >> 1) * 64;
    const int wc = (w & 1) * 64;
    const int el0 = t * 8;
    const short ob = (short)0x3f80;  // bf16 1.0
    const short8 ones = {ob, ob, ob, ob, ob, ob, ob, ob};

    auto stage = [&](int kt, int buf) {
#pragma unroll
        for (int p = 0; p < 2; ++p) {
            const int el = el0 + p * 2048;
            const int row = el >> 5, col = el & 31;
            lds_cp16(Ag + (size_t)row * lda + kt * 32 + col, Alds + buf * 4096 + el);
            lds_cp16(Bg + (size_t)row * ldb + kt * 32 + col, Blds + buf * 4096 + el);
        }
    };

    stage(0, 0);
    int cur = 0;
    for (int kt = 0; kt < ksteps; ++kt) {
        __syncthreads();
        if (kt + 1 < ksteps) stage(kt + 1, cur ^ 1);
        const short8* A8 = (const short8*)(Alds + cur * 4096);
        const short8* B8 = (const short8*)(Blds + cur * 4096);
        short8 a[4], b[4];
#pragma unroll
        for (int i = 0; i < 4; ++i)
            a[i] = A8[(wr + i * 16 + (lane & 15)) * 4 + (lane >> 4)];
#pragma unroll
        for (int j = 0; j < 4; ++j)
            b[j] = B8[(wc + j * 16 + (lane & 15)) * 4 + (lane >> 4)];
#pragma unroll
        for (int i = 0; i < 4; ++i)
#pragma unroll
            for (int j = 0; j < 4; ++j)
                acc[i][j] = __builtin_amdgcn_mfma_f32_16x16x32_bf16(a[i], b[j], acc[i][j], 0, 0, 0);
        if constexpr (ROWSUM) {
#pragma unroll
            for (int i = 0; i < 4; ++i)
                accL[i] = __builtin_amdgcn_mfma_f32_16x16x32_bf16(a[i], ones, accL[i], 0, 0, 0);
        }
        cur ^= 1;
    }
}

// ---------------- kernels ----------------

__global__ void k_cvt_x(const float4* __restrict__ X, ushort4* __restrict__ Xb, int n4) {
    for (int i = blockIdx.x * blockDim.x + threadIdx.x; i < n4; i += gridDim.x * blockDim.x) {
        float4 v = X[i];
        ushort4 o;
        o.x = f2bf(v.x); o.y = f2bf(v.y); o.z = f2bf(v.z); o.w = f2bf(v.w);
        Xb[i] = o;
    }
}

// W[k][n] fp32 -> Wt[z][n][k] bf16; z=0 (Wq) folded with 1/sqrt(2048)
__global__ void k_cvt_w(const float* __restrict__ Wq, const float* __restrict__ Wk,
                        const float* __restrict__ Wv, u16* __restrict__ Wt) {
    int idx = blockIdx.x * 256 + threadIdx.x;  // 3*512*512 total
    int z = idx >> 18;
    int nk = idx & 262143;
    int n = nk >> 9, k = nk & 511;
    const float* W = (z == 0) ? Wq : (z == 1 ? Wk : Wv);
    float v = W[k * 512 + n];
    if (z == 0) v *= 0.022097086912079608f;  // 1/sqrt(2048)
    Wt[idx] = f2bf(v);
}

// ---------------- 8-phase 256^2 projection GEMM ----------------
// C[256x256] = X[256x512] * Wt^T, tile over (mt 0..63, ntl 0..5). 512 thr = 8 waves
// (2M x 4N); per-wave C = 128x64 (8x4 frags). BK=64 as two K32-halves.
// LDS 128KB: L{A,B}[buf][kshalf][256x32 swizzled]. Counted vmcnt(8), raw barriers,
// setprio around MFMA. Stage order: prologue {BK0(0),AK0(0),BK1(0),AK1(0),BK0(1),
// AK0(1)}; in-loop p0:BK1(kt+1) p1:AK1(kt+1) p2:BK0(kt+2) p3:AK0(kt+2).
// Swizzle: rows packed 2 per 128B line; byte ^= ((line&7)<<4) -> 2-way max.
__global__ __launch_bounds__(512, 2) void k_proj8(const u16* __restrict__ Xb, const u16* __restrict__ Wt,
                                                  u16* __restrict__ Qb, u16* __restrict__ Kb,
                                                  u16* __restrict__ Vt) {
    __shared__ alignas(16) u16 LA[2][2][8192];
    __shared__ alignas(16) u16 LB[2][2][8192];
    const int bid = blockIdx.x;            // 384 blocks
    const int mt = (bid & 7) * 8 + ((bid >> 3) & 7);  // 0..63, XCD-chunked
    const int ntl = bid >> 6;              // 0..5
    const int t = threadIdx.x;
    const int lane = t & 63, w = t >> 6;
    const int l15 = lane & 15, g4 = lane >> 4;
    const int wm = w >> 2, wn = w & 3;

    const u16* Ag = Xb + (size_t)mt * 256 * 512;
    const u16* Bg = Wt + (size_t)ntl * 256 * 512;

    // stage one K32-half (256 rows x 32 k = 16KB) of ktile kt
    auto stageH = [&](const u16* gb, u16* lh, int kt, int ks) {
#pragma unroll
        for (int r = 0; r < 2; ++r) {
            const int el = t * 8 + r * 4096;
            const int R2 = el >> 6;
            const int cl = ((el & 63) * 2) ^ ((R2 & 7) << 4);   // logical byte in line
            const int row = R2 * 2 + (cl >> 6);
            const int k = (cl & 63) >> 1;
            lds_cp16(gb + (size_t)row * 512 + kt * 64 + ks * 32 + k, lh + el);
        }
    };
    // read one 16x(k8) MFMA fragment (row=l15-indexed) from a swizzled K-half
    auto frag = [&](const u16* half, int row) -> short8 {
        const int R2 = row >> 1;
        const int c = (((row & 1) << 6) | (g4 << 4)) ^ ((R2 & 7) << 4);
        return *(const short8*)(half + R2 * 64 + (c >> 1));
    };

    f32x4 acc[8][4] = {};

    // prologue: 6 halves (12 loads); need first 2 halves -> vmcnt(8)
    stageH(Bg, &LB[0][0][0], 0, 0);
    stageH(Ag, &LA[0][0][0], 0, 0);
    stageH(Bg, &LB[0][1][0], 0, 1);
    stageH(Ag, &LA[0][1][0], 0, 1);
    stageH(Bg, &LB[1][0][0], 1, 0);
    stageH(Ag, &LA[1][0][0], 1, 0);
    asm volatile("s_waitcnt vmcnt(8)" ::: "memory");
    bar();

#pragma unroll
    for (int kt = 0; kt < 8; ++kt) {
        const int bf = kt & 1;
        short8 a[4], b[4];
        // ---- p0: ks=0, m-quarter 0 (+ B(ks0) reads) ----
#pragma unroll
        for (int nf = 0; nf < 4; ++nf) b[nf] = frag(&LB[bf][0][0], wn * 64 + nf * 16 + l15);
#pragma unroll
        for (int i = 0; i < 4; ++i) a[i] = frag(&LA[bf][0][0], wm * 128 + i * 16 + l15);
        if (kt + 1 < 8) stageH(Bg, &LB[(kt + 1) & 1][1][0], kt + 1, 1);
        bar();
        __builtin_amdgcn_s_setprio(1);
#pragma unroll
        for (int i = 0; i < 4; ++i)
#pragma unroll
            for (int nf = 0; nf < 4; ++nf)
                acc[i][nf] = __builtin_amdgcn_mfma_f32_16x16x32_bf16(a[i], b[nf], acc[i][nf], 0, 0, 0);
        __builtin_amdgcn_s_setprio(0);
        // ---- p1: ks=0, m-quarter 1 (B reused in regs) ----
#pragma unroll
        for (int i = 0; i < 4; ++i) a[i] = frag(&LA[bf][0][0], wm * 128 + 64 + i * 16 + l15);
        if (kt + 1 < 8) stageH(Ag, &LA[(kt + 1) & 1][1][0], kt + 1, 1);
        if (kt < 7) asm volatile("s_waitcnt vmcnt(8)" ::: "memory");
        else        asm volatile("s_waitcnt vmcnt(0)" ::: "memory");
        bar();
        __builtin_amdgcn_s_setprio(1);
#pragma unroll
        for (int i = 0; i < 4; ++i)
#pragma unroll
            for (int nf = 0; nf < 4; ++nf)
                acc[4 + i][nf] = __builtin_amdgcn_mfma_f32_16x16x32_bf16(a[i], b[nf], acc[4 + i][nf], 0, 0, 0);
        __builtin_amdgcn_s_setprio(0);
        // ---- p2: ks=1, m-quarter 0 (+ B(ks1) reads) ----
#pragma unroll
        for (int nf = 0; nf < 4; ++nf) b[nf] = frag(&LB[bf][1][0], wn * 64 + nf * 16 + l15);
#pragma unroll
        for (int i = 0; i < 4; ++i) a[i] = frag(&LA[bf][1][0], wm * 128 + i * 16 + l15);
        if (kt + 2 < 8) stageH(Bg, &LB[kt & 1][0][0], kt + 2, 0);
        bar();
        __builtin_amdgcn_s_setprio(1);
#pragma unroll
        for (int i = 0; i < 4; ++i)
#pragma unroll
            for (int nf = 0; nf < 4; ++nf)
                acc[i][nf] = __builtin_amdgcn_mfma_f32_16x16x32_bf16(a[i], b[nf], acc[i][nf], 0, 0, 0);
        __builtin_amdgcn_s_setprio(0);
        // ---- p3: ks=1, m-quarter 1 ----
#pragma unroll
        for (int i = 0; i < 4; ++i) a[i] = frag(&LA[bf][1][0], wm * 128 + 64 + i * 16 + l15);
        if (kt + 2 < 8) stageH(Ag, &LA[kt & 1][0][0], kt + 2, 0);
        if (kt < 6)      asm volatile("s_waitcnt vmcnt(8)" ::: "memory");
        else if (kt == 6) asm volatile("s_waitcnt vmcnt(4)" ::: "memory");
        bar();
        __builtin_amdgcn_s_setprio(1);
#pragma unroll
        for (int i = 0; i < 4; ++i)
#pragma unroll
            for (int nf = 0; nf < 4; ++nf)
                acc[4 + i][nf] = __builtin_amdgcn_mfma_f32_16x16x32_bf16(a[i], b[nf], acc[4 + i][nf], 0, 0, 0);
        __builtin_amdgcn_s_setprio(0);
    }

    // ---- epilogue ----
    const int z = ntl >> 1;
    const int nc0 = (ntl & 1) * 256 + wn * 64;
    const int m0 = mt * 256 + wm * 128;
    if (z < 2) {
        u16* O = (z == 0) ? Qb : Kb;
#pragma unroll
        for (int mf = 0; mf < 8; ++mf)
#pragma unroll
            for (int nf = 0; nf < 4; ++nf)
#pragma unroll
                for (int r = 0; r < 4; ++r)
                    O[(size_t)(m0 + mf * 16 + 4 * g4 + r) * 512 + nc0 + nf * 16 + l15] = f2bf(acc[mf][nf][r]);
    } else {
        const int b = mt >> 3;
#pragma unroll
        for (int mf = 0; mf < 8; ++mf)
#pragma unroll
            for (int nf = 0; nf < 4; ++nf) {
                const int s0 = (mt & 7) * 256 + wm * 128 + mf * 16 + 4 * g4;
                const int d = nc0 + nf * 16 + l15;
                ushort4 pk;
                pk.x = f2bf(acc[mf][nf][0]); pk.y = f2bf(acc[mf][nf][1]);
                pk.z = f2bf(acc[mf][nf][2]); pk.w = f2bf(acc[mf][nf][3]);
                *(ushort4*)(Vt + (size_t)b * 512 * 2048 + (size_t)d * 2048 + s0) = pk;
            }
    }
}

// scores: P[b][q][kv] = exp(q.k/sqrt(S)) masked causal, unnormalized, bf16
__global__ __launch_bounds__(256, 4) void k_scores(const u16* __restrict__ Qb, const u16* __restrict__ Kb,
                                                   u16* __restrict__ P) {
    const int bid = blockIdx.x;
    const int bz = bid & 7;
    const int tt = bid >> 3;  // 0..135
    int qi = (int)((sqrtf(8.0f * tt + 1.0f) - 1.0f) * 0.5f);
    while ((qi + 1) * (qi + 2) / 2 <= tt) ++qi;
    while (qi * (qi + 1) / 2 > tt) --qi;
    const int kvj = tt - qi * (qi + 1) / 2;  // 0..qi

    __shared__ alignas(16) u16 Alds[2][4096];
    __shared__ alignas(16) u16 Blds[2][4096];
    const u16* Ag = Qb + (size_t)bz * 2048 * 512 + (size_t)qi * 128 * 512;
    const u16* Bg = Kb + (size_t)bz * 2048 * 512 + (size_t)kvj * 128 * 512;
    f32x4 acc[4][4] = {};
    gemm_core<false>(Ag, 512, Bg, 512, 16, &Alds[0][0], &Blds[0][0], acc, (f32x4*)nullptr);

    const int t = threadIdx.x, lane = t & 63, w = t >> 6;
    const int wr = (w >> 1) * 64, wc = (w & 1) * 64;
    u16* Pb = P + (size_t)bz * 2048 * 2048;
#pragma unroll
    for (int i = 0; i < 4; ++i)
#pragma unroll
        for (int j = 0; j < 4; ++j)
#pragma unroll
            for (int r = 0; r < 4; ++r) {
                int q = qi * 128 + wr + i * 16 + 4 * (lane >> 4) + r;
                int kv = kvj * 128 + wc + j * 16 + (lane & 15);
                float pv = (kv <= q) ? __expf(acc[i][j][r]) : 0.0f;
                Pb[(size_t)q * 2048 + kv] = f2bf(pv);
            }
}

// PV: out = (P @ Vt) / rowsum(P); rowsum via ones-MFMA.
__global__ __launch_bounds__(256, 4) void k_pv(const u16* __restrict__ P, const u16* __restrict__ Vt,
                                               float* __restrict__ Out) {
    __shared__ alignas(16) u16 Alds[2][2048];
    __shared__ alignas(16) u16 Blds[2][4096];
    const int bid = blockIdx.x;
    const int bz = bid & 7;
    const int u = bid >> 3;        // 0..127
    const int g = u >> 5;
    const int s = u & 31;
    const int nt = g;
    const int qi2 = (g & 1) ? (31 - s) : s;
    const int ksteps = (qi2 + 1) * 2;

    const int t = threadIdx.x, lane = t & 63, w = t >> 6;
    const int l = lane & 15, g4 = lane >> 4;
    const int wr = (w >> 1) * 32, wc = (w & 1) * 64;
    const u16* Ag = P + (size_t)bz * 2048 * 2048 + (size_t)qi2 * 64 * 2048;
    const u16* Bg = Vt + (size_t)bz * 512 * 2048 + (size_t)nt * 128 * 2048;
    const short ob = (short)0x3f80;
    const short8 ones = {ob, ob, ob, ob, ob, ob, ob, ob};

    auto stage = [&](int kt, int buf) {
        {
            const int el = t * 8;
            const int row = el >> 5, col = el & 31;
            lds_cp16(Ag + (size_t)row * 2048 + kt * 32 + col, &Alds[buf][el]);
        }
#pragma unroll
        for (int p = 0; p < 2; ++p) {
            const int el = t * 8 + p * 2048;
            const int row = el >> 5, col = el & 31;
            lds_cp16(Bg + (size_t)row * 2048 + kt * 32 + col, &Blds[buf][el]);
        }
    };

    f32x4 acc[2][4] = {};
    f32x4 accL[2] = {};
    stage(0, 0);
    int cur = 0;
    for (int kt = 0; kt < ksteps; ++kt) {
        __syncthreads();
        if (kt + 1 < ksteps) stage(kt + 1, cur ^ 1);
        const short8* A8 = (const short8*)&Alds[cur][0];
        const short8* B8 = (const short8*)&Blds[cur][0];
        short8 a[2], b[4];
#pragma unroll
        for (int i = 0; i < 2; ++i) a[i] = A8[(wr + i * 16 + l) * 4 + g4];
#pragma unroll
        for (int j = 0; j < 4; ++j) b[j] = B8[(wc + j * 16 + l) * 4 + g4];
#pragma unroll
        for (int i = 0; i < 2; ++i) {
#pragma unroll
            for (int j = 0; j < 4; ++j)
                acc[i][j] = __builtin_amdgcn_mfma_f32_16x16x32_bf16(a[i], b[j], acc[i][j], 0, 0, 0);
            accL[i] = __builtin_amdgcn_mfma_f32_16x16x32_bf16(a[i], ones, accL[i], 0, 0, 0);
        }
        cur ^= 1;
    }

#pragma unroll
    for (int i = 0; i < 2; ++i) {
        float inv[4];
#pragma unroll
        for (int r = 0; r < 4; ++r) inv[r] = 1.0f / accL[i][r];
#pragma unroll
        for (int j = 0; j < 4; ++j) {
            const int d = nt * 128 + wc + j * 16 + l;
#pragma unroll
            for (int r = 0; r < 4; ++r) {
                const int q = qi2 * 64 + wr + i * 16 + 4 * g4 + r;
                Out[(size_t)bz * 2048 * 512 + (size_t)q * 512 + d] = acc[i][j][r] * inv[r];
            }
        }
    }
}

// ---------------- launch ----------------

extern "C" void kernel_launch(void* const* d_in, const int* in_sizes, int n_in,
                              void* d_out, int out_size, void* d_ws, size_t ws_size,
                              hipStream_t stream) {
    const float* data = (const float*)d_in[0];
    const float* Wq = (const float*)d_in[1];
    const float* Wk = (const float*)d_in[2];
    const float* Wv = (const float*)d_in[3];
    float* out = (float*)d_out;
    char* ws = (char*)d_ws;

    // workspace layout (bytes)
    u16* Xb = (u16*)(ws);                 // 16 MB  [16384][512] bf16 data
    u16* Qb = (u16*)(ws + 16777216);      // 16 MB  Q (scale folded in Wq)
    u16* Kb = (u16*)(ws + 33554432);      // 16 MB  K
    u16* Vt = (u16*)(ws + 50331648);      // 16 MB  V^T [b][d][s]
    u16* Wt = (u16*)(ws + 67108864);      // 1.5 MB [3][n][k] bf16 W^T
    u16* P  = (u16*)(ws + 68681728);      // 64 MB  [b][q][kv] bf16 exp(scores)

    k_cvt_x<<<2048, 256, 0, stream>>>((const float4*)data, (ushort4*)Xb, (8 * 2048 * 512) / 4);
    k_cvt_w<<<3072, 256, 0, stream>>>(Wq, Wk, Wv, Wt);
    k_proj8<<<384, 512, 0, stream>>>(Xb, Wt, Qb, Kb, Vt);
    k_scores<<<1088, 256, 0, stream>>>(Qb, Kb, P);
    k_pv<<<1024, 256, 0, stream>>>(P, Vt, out);
}

// Round 8
// 112.411 us; speedup vs baseline: 1.2299x; 1.2299x over previous
//
#include <hip/hip_runtime.h>

typedef unsigned short u16;
typedef __attribute__((ext_vector_type(8))) short short8;
typedef __attribute__((ext_vector_type(4))) float f32x4;

// ---------------- helpers ----------------

__device__ __forceinline__ u16 f2bf(float f) {
    unsigned u = __float_as_uint(f);
    u += 0x7fffu + ((u >> 16) & 1u);   // round-to-nearest-even
    return (u16)(u >> 16);
}

// async global->LDS 16B copy; per-lane dst == wave-uniform base + lane*16.
__device__ __forceinline__ void lds_cp16(const u16* g, u16* l) {
#if defined(__has_builtin) && __has_builtin(__builtin_amdgcn_global_load_lds)
    __builtin_amdgcn_global_load_lds(
        (const __attribute__((address_space(1))) void*)g,
        (__attribute__((address_space(3))) void*)l, 16, 0, 0);
#else
    *(uint4*)l = *(const uint4*)g;
#endif
}

// ---------------- shared GEMM core, BK=64, swizzled LDS ----------------
// C[(MI*32) x 128] += A * B^T; A row-major [row][k] (lda), Bt row-major [col][k] (ldb).
// 256 thr = 4 waves; wave w owns rows [(w>>1)*MI*16 ..) x cols [(w&1)*64 ..).
// LDS row stride 128B; granule g (16B) of row r stored at g^(r&7) (linear glds dst,
// SOURCE granule inverse-permuted -> rule 21). Reads XOR the same -> identity on src,
// 2-way bank aliasing max (free, m136). K-granule permutation identical on A and B
// so it cancels inside MFMA. 2 barriers/kstep; latency hidden by 4 blocks/CU.
template <int MI, bool ROWSUM>
__device__ __forceinline__ void gemm64(const u16* __restrict__ Ag, int lda,
                                       const u16* __restrict__ Bg, int ldb,
                                       int ksteps, u16* Alds, u16* Blds,
                                       f32x4 (&acc)[MI][4], f32x4* accL) {
    const int t = threadIdx.x;
    const int lane = t & 63, w = t >> 6;
    const int l15 = lane & 15, g4 = lane >> 4;
    const int wr = (w >> 1) * (MI * 16);
    const int wc = (w & 1) * 64;
    const int swz = l15 & 7;
    const short ob = (short)0x3f80;  // bf16 1.0
    const short8 ones = {ob, ob, ob, ob, ob, ob, ob, ob};

    for (int kt = 0; kt < ksteps; ++kt) {
        __syncthreads();  // prior kstep's reads complete before overwrite
#pragma unroll
        for (int p = 0; p < MI; ++p) {  // A: MI*32 rows -> MI granules/thread
            const int gi = t + p * 256;
            const int row = gi >> 3;
            const int gl = (gi & 7) ^ (row & 7);
            lds_cp16(Ag + (size_t)row * lda + kt * 64 + gl * 8, Alds + gi * 8);
        }
#pragma unroll
        for (int p = 0; p < 4; ++p) {   // B: 128 rows -> 4 granules/thread
            const int gi = t + p * 256;
            const int row = gi >> 3;
            const int gl = (gi & 7) ^ (row & 7);
            lds_cp16(Bg + (size_t)row * ldb + kt * 64 + gl * 8, Blds + gi * 8);
        }
        __syncthreads();  // barrier drains vmcnt -> tile visible
#pragma unroll
        for (int ks = 0; ks < 2; ++ks) {
            short8 a[MI], b[4];
#pragma unroll
            for (int i = 0; i < MI; ++i) {
                const int r = wr + i * 16 + l15;
                a[i] = *(const short8*)(Alds + r * 64 + (((ks * 4 + g4) ^ swz) * 8));
            }
#pragma unroll
            for (int j = 0; j < 4; ++j) {
                const int r = wc + j * 16 + l15;
                b[j] = *(const short8*)(Blds + r * 64 + (((ks * 4 + g4) ^ swz) * 8));
            }
#pragma unroll
            for (int i = 0; i < MI; ++i)
#pragma unroll
                for (int j = 0; j < 4; ++j)
                    acc[i][j] = __builtin_amdgcn_mfma_f32_16x16x32_bf16(a[i], b[j], acc[i][j], 0, 0, 0);
            if constexpr (ROWSUM) {
#pragma unroll
                for (int i = 0; i < MI; ++i)
                    accL[i] = __builtin_amdgcn_mfma_f32_16x16x32_bf16(a[i], ones, accL[i], 0, 0, 0);
            }
        }
    }
}

// ---------------- kernels ----------------

// data fp32 -> bf16 (vectorized)
__global__ void k_cvt_x(const float4* __restrict__ X, ushort4* __restrict__ Xb, int n4) {
    for (int i = blockIdx.x * blockDim.x + threadIdx.x; i < n4; i += gridDim.x * blockDim.x) {
        float4 v = X[i];
        ushort4 o;
        o.x = f2bf(v.x); o.y = f2bf(v.y); o.z = f2bf(v.z); o.w = f2bf(v.w);
        Xb[i] = o;
    }
}

// Weights -> bf16. z=0: Wq NATIVE [k][n]; z=1: Wk NATIVE [k][n] (both are pure
// casts, coalesced). z=2: Wv transposed [n][k] (B-operand for V projection).
__global__ void k_cvt_w(const float* __restrict__ Wq, const float* __restrict__ Wk,
                        const float* __restrict__ Wv, u16* __restrict__ Wt) {
    int idx = blockIdx.x * 256 + threadIdx.x;  // 3*512*512 total
    int z = idx >> 18;
    int rem = idx & 262143;
    float v;
    if (z == 0) v = Wq[rem];                       // native copy
    else if (z == 1) v = Wk[rem];                  // native copy
    else { int n = rem >> 9, k = rem & 511; v = Wv[k * 512 + n]; }  // transpose
    Wt[idx] = f2bf(v);
}

// M[e][f] = sum_n Wq[e,n] * Wk[f,n]  (Wq Wk^T, contraction over COLUMN index n).
// gemm_bt with A = Wq native (rows e, k=n), B = Wk native (rows f, k=n).
// Store Mt[f*512+e] = M[e][f]/sqrt(2048)  -> Mt[n'][k'] = M[k',n'] as k_proj needs.
__global__ __launch_bounds__(256, 4) void k_gemm_m(const u16* __restrict__ Wt, u16* __restrict__ Mt) {
    __shared__ alignas(16) u16 Alds[8192];
    __shared__ alignas(16) u16 Blds[8192];
    const int mt = blockIdx.x & 3, nt = blockIdx.x >> 2;
    const u16* Ag = Wt + 0 * 512 * 512 + (size_t)mt * 128 * 512;  // Wq native rows (e)
    const u16* Bg = Wt + 1 * 512 * 512 + (size_t)nt * 128 * 512;  // Wk native rows (f)
    f32x4 acc[4][4] = {};
    gemm64<4, false>(Ag, 512, Bg, 512, 8, Alds, Blds, acc, (f32x4*)nullptr);

    const int t = threadIdx.x, lane = t & 63, w = t >> 6;
    const int wr = (w >> 1) * 64, wc = (w & 1) * 64;
    const float sc = 0.022097086912079608f;  // 1/sqrt(2048)
#pragma unroll
    for (int i = 0; i < 4; ++i)
#pragma unroll
        for (int j = 0; j < 4; ++j)
#pragma unroll
            for (int r = 0; r < 4; ++r) {
                int e = mt * 128 + wr + i * 16 + 4 * (lane >> 4) + r;  // A row
                int f = nt * 128 + wc + j * 16 + (lane & 15);          // B row
                Mt[(size_t)f * 512 + e] = f2bf(acc[i][j][r] * sc);     // TRANSPOSED store
            }
}

// projections: z=0 -> G = Xb*Mt^T (replaces Q; K projection deleted),
//              z=1 -> V stored transposed [b][d][s]
__global__ __launch_bounds__(256, 4) void k_proj(const u16* __restrict__ Xb, const u16* __restrict__ Wt,
                                                 const u16* __restrict__ Mt,
                                                 u16* __restrict__ Gb, u16* __restrict__ Vt) {
    __shared__ alignas(16) u16 Alds[8192];
    __shared__ alignas(16) u16 Blds[8192];
    const int bid = blockIdx.x;            // 1024 blocks
    const int u = bid >> 3;                // 0..127
    const int z = u >> 6;                  // 0..1
    const int nt = (u >> 4) & 3;           // 0..3
    const int mt = (bid & 7) * 16 + (u & 15);  // 0..127, XCD-chunked
    const u16* Ag = Xb + (size_t)mt * 128 * 512;
    const u16* Bg = (z == 0) ? (Mt + (size_t)nt * 128 * 512)
                             : (Wt + 2 * 512 * 512 + (size_t)nt * 128 * 512);
    f32x4 acc[4][4] = {};
    gemm64<4, false>(Ag, 512, Bg, 512, 8, Alds, Blds, acc, (f32x4*)nullptr);

    const int t = threadIdx.x, lane = t & 63, w = t >> 6;
    const int wr = (w >> 1) * 64, wc = (w & 1) * 64;
    if (z == 0) {
#pragma unroll
        for (int i = 0; i < 4; ++i)
#pragma unroll
            for (int j = 0; j < 4; ++j)
#pragma unroll
                for (int r = 0; r < 4; ++r) {
                    int m = mt * 128 + wr + i * 16 + 4 * (lane >> 4) + r;
                    int n = nt * 128 + wc + j * 16 + (lane & 15);
                    Gb[(size_t)m * 512 + n] = f2bf(acc[i][j][r]);
                }
    } else {
        int b = mt >> 4;  // 16 m-tiles per batch
#pragma unroll
        for (int i = 0; i < 4; ++i)
#pragma unroll
            for (int j = 0; j < 4; ++j) {
                int s0 = (mt * 128 + wr + i * 16 + 4 * (lane >> 4)) & 2047;
                int d = nt * 128 + wc + j * 16 + (lane & 15);
                ushort4 pk;
                pk.x = f2bf(acc[i][j][0]); pk.y = f2bf(acc[i][j][1]);
                pk.z = f2bf(acc[i][j][2]); pk.w = f2bf(acc[i][j][3]);
                *(ushort4*)(Vt + (size_t)b * 512 * 2048 + (size_t)d * 2048 + s0) = pk;
            }
    }
}

// scores: P[b][q][kv] = exp(G . X) causal-masked, unnormalized, bf16.
// B-operand is Xb itself (K projection eliminated algebraically).
__global__ __launch_bounds__(256, 4) void k_scores(const u16* __restrict__ Gb, const u16* __restrict__ Xb,
                                                   u16* __restrict__ P) {
    const int bid = blockIdx.x;
    const int bz = bid & 7;
    const int tt = bid >> 3;  // 0..135
    int qi = (int)((sqrtf(8.0f * tt + 1.0f) - 1.0f) * 0.5f);
    while ((qi + 1) * (qi + 2) / 2 <= tt) ++qi;
    while (qi * (qi + 1) / 2 > tt) --qi;
    const int kvj = tt - qi * (qi + 1) / 2;  // 0..qi

    __shared__ alignas(16) u16 Alds[8192];
    __shared__ alignas(16) u16 Blds[8192];
    const u16* Ag = Gb + (size_t)bz * 2048 * 512 + (size_t)qi * 128 * 512;
    const u16* Bg = Xb + (size_t)bz * 2048 * 512 + (size_t)kvj * 128 * 512;
    f32x4 acc[4][4] = {};
    gemm64<4, false>(Ag, 512, Bg, 512, 8, Alds, Blds, acc, (f32x4*)nullptr);

    const int t = threadIdx.x, lane = t & 63, w = t >> 6;
    const int wr = (w >> 1) * 64, wc = (w & 1) * 64;
    u16* Pb = P + (size_t)bz * 2048 * 2048;
#pragma unroll
    for (int i = 0; i < 4; ++i)
#pragma unroll
        for (int j = 0; j < 4; ++j)
#pragma unroll
            for (int r = 0; r < 4; ++r) {
                int q = qi * 128 + wr + i * 16 + 4 * (lane >> 4) + r;
                int kv = kvj * 128 + wc + j * 16 + (lane & 15);
                float pv = (kv <= q) ? __expf(acc[i][j][r]) : 0.0f;
                Pb[(size_t)q * 2048 + kv] = f2bf(pv);
            }
}

// PV: out = (P @ Vt) / rowsum(P); rowsum via ones-MFMA. BK=64, 24KB LDS.
// 1024 blocks; bz = bid&7 (XCD/batch affinity); quarter mapping keeps per-CU
// work constant (pairs qi2 and 31-qi2).
__global__ __launch_bounds__(256, 4) void k_pv(const u16* __restrict__ P, const u16* __restrict__ Vt,
                                               float* __restrict__ Out) {
    __shared__ alignas(16) u16 Alds[4096];   // 64q x 64kv
    __shared__ alignas(16) u16 Blds[8192];   // 128d x 64kv
    const int bid = blockIdx.x;
    const int bz = bid & 7;
    const int u = bid >> 3;        // 0..127
    const int g = u >> 5;          // quarter = nt
    const int s = u & 31;
    const int nt = g;
    const int qi2 = (g & 1) ? (31 - s) : s;   // 64-row q tile
    const int ksteps = qi2 + 1;               // causal extent in 64-wide kv tiles

    const u16* Ag = P + (size_t)bz * 2048 * 2048 + (size_t)qi2 * 64 * 2048;
    const u16* Bg = Vt + (size_t)bz * 512 * 2048 + (size_t)nt * 128 * 2048;
    f32x4 acc[2][4] = {};
    f32x4 accL[2] = {};
    gemm64<2, true>(Ag, 2048, Bg, 2048, ksteps, Alds, Blds, acc, accL);

    const int t = threadIdx.x, lane = t & 63, w = t >> 6;
    const int l = lane & 15, g4 = lane >> 4;
    const int wr = (w >> 1) * 32, wc = (w & 1) * 64;
#pragma unroll
    for (int i = 0; i < 2; ++i) {
        float inv[4];
#pragma unroll
        for (int r = 0; r < 4; ++r) inv[r] = 1.0f / accL[i][r];
#pragma unroll
        for (int j = 0; j < 4; ++j) {
            const int d = nt * 128 + wc + j * 16 + l;
#pragma unroll
            for (int r = 0; r < 4; ++r) {
                const int q = qi2 * 64 + wr + i * 16 + 4 * g4 + r;
                Out[(size_t)bz * 2048 * 512 + (size_t)q * 512 + d] = acc[i][j][r] * inv[r];
            }
        }
    }
}

// ---------------- launch ----------------

extern "C" void kernel_launch(void* const* d_in, const int* in_sizes, int n_in,
                              void* d_out, int out_size, void* d_ws, size_t ws_size,
                              hipStream_t stream) {
    const float* data = (const float*)d_in[0];
    const float* Wq = (const float*)d_in[1];
    const float* Wk = (const float*)d_in[2];
    const float* Wv = (const float*)d_in[3];
    float* out = (float*)d_out;
    char* ws = (char*)d_ws;

    // workspace layout (bytes)
    u16* Xb = (u16*)(ws);                 // 16 MB  [16384][512] bf16 data
    u16* Gb = (u16*)(ws + 16777216);      // 16 MB  G = X*M (replaces Q)
    u16* Mt = (u16*)(ws + 33554432);      // 512 KB [n'][k'] bf16 = M^T, scaled
    u16* Vt = (u16*)(ws + 50331648);      // 16 MB  V^T [b][d][s]
    u16* Wt = (u16*)(ws + 67108864);      // 1.5 MB bf16 {Wq native, Wk native, Wv^T}
    u16* P  = (u16*)(ws + 68681728);      // 64 MB  [b][q][kv] bf16 exp(scores)

    k_cvt_x<<<2048, 256, 0, stream>>>((const float4*)data, (ushort4*)Xb, (8 * 2048 * 512) / 4);
    k_cvt_w<<<3072, 256, 0, stream>>>(Wq, Wk, Wv, Wt);
    k_gemm_m<<<16, 256, 0, stream>>>(Wt, Mt);
    k_proj<<<1024, 256, 0, stream>>>(Xb, Wt, Mt, Gb, Vt);
    k_scores<<<1088, 256, 0, stream>>>(Gb, Xb, P);
    k_pv<<<1024, 256, 0, stream>>>(P, Vt, out);
}

// Round 9
// 111.003 us; speedup vs baseline: 1.2455x; 1.0127x over previous
//
#include <hip/hip_runtime.h>

typedef unsigned short u16;
typedef __attribute__((ext_vector_type(8))) short short8;
typedef __attribute__((ext_vector_type(4))) float f32x4;

// ---------------- helpers ----------------

__device__ __forceinline__ u16 f2bf(float f) {
    unsigned u = __float_as_uint(f);
    u += 0x7fffu + ((u >> 16) & 1u);   // round-to-nearest-even
    return (u16)(u >> 16);
}

// async global->LDS 16B copy; per-lane dst == wave-uniform base + lane*16.
__device__ __forceinline__ void lds_cp16(const u16* g, u16* l) {
#if defined(__has_builtin) && __has_builtin(__builtin_amdgcn_global_load_lds)
    __builtin_amdgcn_global_load_lds(
        (const __attribute__((address_space(1))) void*)g,
        (__attribute__((address_space(3))) void*)l, 16, 0, 0);
#else
    *(uint4*)l = *(const uint4*)g;
#endif
}

// De-convoy: blocks on the same CU (same bid mod 256 cohort) start phase-shifted
// by ~450 cyc per resident slot, so their stage/drain/compute phases interleave
// instead of aligning (identical-work blocks otherwise run barrier-locked and
// all drain simultaneously -> CU idles; MfmaUtil ~20% regardless of residency).
__device__ __forceinline__ void skew(int bid) {
    const int slot = bid >> 8;
    for (int i = 0; i < slot; ++i) __builtin_amdgcn_s_sleep(7);  // 7*64 = 448 cyc each
}

// ---------------- shared GEMM core, BK=64, swizzled LDS ----------------
// C[(MI*32) x 128] += A * B^T; A row-major [row][k] (lda), Bt row-major [col][k] (ldb).
// 256 thr = 4 waves; wave w owns rows [(w>>1)*MI*16 ..) x cols [(w&1)*64 ..).
// LDS row stride 128B; granule g (16B) of row r stored at g^(r&7) (linear glds dst,
// SOURCE granule inverse-permuted -> rule 21). Reads XOR the same -> identity on src,
// 2-way bank aliasing max (free, m136). K-granule permutation identical on A and B
// so it cancels inside MFMA. 2 barriers/kstep; inter-block overlap via skew().
template <int MI, bool ROWSUM>
__device__ __forceinline__ void gemm64(const u16* __restrict__ Ag, int lda,
                                       const u16* __restrict__ Bg, int ldb,
                                       int ksteps, u16* Alds, u16* Blds,
                                       f32x4 (&acc)[MI][4], f32x4* accL) {
    const int t = threadIdx.x;
    const int lane = t & 63, w = t >> 6;
    const int l15 = lane & 15, g4 = lane >> 4;
    const int wr = (w >> 1) * (MI * 16);
    const int wc = (w & 1) * 64;
    const int swz = l15 & 7;
    const short ob = (short)0x3f80;  // bf16 1.0
    const short8 ones = {ob, ob, ob, ob, ob, ob, ob, ob};

    for (int kt = 0; kt < ksteps; ++kt) {
        __syncthreads();  // prior kstep's reads complete before overwrite
#pragma unroll
        for (int p = 0; p < MI; ++p) {  // A: MI*32 rows -> MI granules/thread
            const int gi = t + p * 256;
            const int row = gi >> 3;
            const int gl = (gi & 7) ^ (row & 7);
            lds_cp16(Ag + (size_t)row * lda + kt * 64 + gl * 8, Alds + gi * 8);
        }
#pragma unroll
        for (int p = 0; p < 4; ++p) {   // B: 128 rows -> 4 granules/thread
            const int gi = t + p * 256;
            const int row = gi >> 3;
            const int gl = (gi & 7) ^ (row & 7);
            lds_cp16(Bg + (size_t)row * ldb + kt * 64 + gl * 8, Blds + gi * 8);
        }
        __syncthreads();  // barrier drains vmcnt -> tile visible
#pragma unroll
        for (int ks = 0; ks < 2; ++ks) {
            short8 a[MI], b[4];
#pragma unroll
            for (int i = 0; i < MI; ++i) {
                const int r = wr + i * 16 + l15;
                a[i] = *(const short8*)(Alds + r * 64 + (((ks * 4 + g4) ^ swz) * 8));
            }
#pragma unroll
            for (int j = 0; j < 4; ++j) {
                const int r = wc + j * 16 + l15;
                b[j] = *(const short8*)(Blds + r * 64 + (((ks * 4 + g4) ^ swz) * 8));
            }
#pragma unroll
            for (int i = 0; i < MI; ++i)
#pragma unroll
                for (int j = 0; j < 4; ++j)
                    acc[i][j] = __builtin_amdgcn_mfma_f32_16x16x32_bf16(a[i], b[j], acc[i][j], 0, 0, 0);
            if constexpr (ROWSUM) {
#pragma unroll
                for (int i = 0; i < MI; ++i)
                    accL[i] = __builtin_amdgcn_mfma_f32_16x16x32_bf16(a[i], ones, accL[i], 0, 0, 0);
            }
        }
    }
}

// ---------------- kernels ----------------

// fused input conversion: blocks [0,2048) -> data fp32->bf16 (float4-vectorized,
// grid-stride); blocks [2048,2816) -> weights (Wq,Wk native cast; Wv transposed).
__global__ void k_cvt(const float4* __restrict__ X4, ushort4* __restrict__ Xb4,
                      const float* __restrict__ Wq, const float* __restrict__ Wk,
                      const float* __restrict__ Wv, u16* __restrict__ Wt) {
    const int bid = blockIdx.x, t = threadIdx.x;
    if (bid < 2048) {
        const int n4 = (8 * 2048 * 512) / 4;
        for (int i = bid * 256 + t; i < n4; i += 2048 * 256) {
            float4 v = X4[i];
            ushort4 o;
            o.x = f2bf(v.x); o.y = f2bf(v.y); o.z = f2bf(v.z); o.w = f2bf(v.w);
            Xb4[i] = o;
        }
    } else {
        const int e0 = ((bid - 2048) * 256 + t) * 4;  // 4 elems/thread of 786432
#pragma unroll
        for (int p = 0; p < 4; ++p) {
            const int idx = e0 + p;
            const int z = idx >> 18;
            const int rem = idx & 262143;
            float v;
            if (z == 0) v = Wq[rem];                       // native copy [k][n]
            else if (z == 1) v = Wk[rem];                  // native copy [k][n]
            else { int n = rem >> 9, k = rem & 511; v = Wv[k * 512 + n]; }  // transpose
            Wt[idx] = f2bf(v);
        }
    }
}

// M[e][f] = sum_n Wq[e,n] * Wk[f,n]  (Wq Wk^T, contraction over COLUMN index n).
// Store Mt[f*512+e] = M[e][f]/sqrt(2048)  -> Mt[n'][k'] = M[k',n'] as k_proj needs.
__global__ __launch_bounds__(256, 4) void k_gemm_m(const u16* __restrict__ Wt, u16* __restrict__ Mt) {
    __shared__ alignas(16) u16 Alds[8192];
    __shared__ alignas(16) u16 Blds[8192];
    const int mt = blockIdx.x & 3, nt = blockIdx.x >> 2;
    const u16* Ag = Wt + 0 * 512 * 512 + (size_t)mt * 128 * 512;  // Wq native rows (e)
    const u16* Bg = Wt + 1 * 512 * 512 + (size_t)nt * 128 * 512;  // Wk native rows (f)
    f32x4 acc[4][4] = {};
    gemm64<4, false>(Ag, 512, Bg, 512, 8, Alds, Blds, acc, (f32x4*)nullptr);

    const int t = threadIdx.x, lane = t & 63, w = t >> 6;
    const int wr = (w >> 1) * 64, wc = (w & 1) * 64;
    const float sc = 0.022097086912079608f;  // 1/sqrt(2048)
#pragma unroll
    for (int i = 0; i < 4; ++i)
#pragma unroll
        for (int j = 0; j < 4; ++j)
#pragma unroll
            for (int r = 0; r < 4; ++r) {
                int e = mt * 128 + wr + i * 16 + 4 * (lane >> 4) + r;  // A row
                int f = nt * 128 + wc + j * 16 + (lane & 15);          // B row
                Mt[(size_t)f * 512 + e] = f2bf(acc[i][j][r] * sc);     // TRANSPOSED store
            }
}

// projections: z=0 -> G = Xb*Mt^T (replaces Q; K projection deleted),
//              z=1 -> V stored transposed [b][d][s]
__global__ __launch_bounds__(256, 4) void k_proj(const u16* __restrict__ Xb, const u16* __restrict__ Wt,
                                                 const u16* __restrict__ Mt,
                                                 u16* __restrict__ Gb, u16* __restrict__ Vt) {
    __shared__ alignas(16) u16 Alds[8192];
    __shared__ alignas(16) u16 Blds[8192];
    const int bid = blockIdx.x;            // 1024 blocks
    const int u = bid >> 3;                // 0..127
    const int z = u >> 6;                  // 0..1
    const int nt = (u >> 4) & 3;           // 0..3
    const int mt = (bid & 7) * 16 + (u & 15);  // 0..127, XCD-chunked
    const u16* Ag = Xb + (size_t)mt * 128 * 512;
    const u16* Bg = (z == 0) ? (Mt + (size_t)nt * 128 * 512)
                             : (Wt + 2 * 512 * 512 + (size_t)nt * 128 * 512);
    skew(bid);
    f32x4 acc[4][4] = {};
    gemm64<4, false>(Ag, 512, Bg, 512, 8, Alds, Blds, acc, (f32x4*)nullptr);

    const int t = threadIdx.x, lane = t & 63, w = t >> 6;
    const int wr = (w >> 1) * 64, wc = (w & 1) * 64;
    if (z == 0) {
#pragma unroll
        for (int i = 0; i < 4; ++i)
#pragma unroll
            for (int j = 0; j < 4; ++j)
#pragma unroll
                for (int r = 0; r < 4; ++r) {
                    int m = mt * 128 + wr + i * 16 + 4 * (lane >> 4) + r;
                    int n = nt * 128 + wc + j * 16 + (lane & 15);
                    Gb[(size_t)m * 512 + n] = f2bf(acc[i][j][r]);
                }
    } else {
        int b = mt >> 4;  // 16 m-tiles per batch
#pragma unroll
        for (int i = 0; i < 4; ++i)
#pragma unroll
            for (int j = 0; j < 4; ++j) {
                int s0 = (mt * 128 + wr + i * 16 + 4 * (lane >> 4)) & 2047;
                int d = nt * 128 + wc + j * 16 + (lane & 15);
                ushort4 pk;
                pk.x = f2bf(acc[i][j][0]); pk.y = f2bf(acc[i][j][1]);
                pk.z = f2bf(acc[i][j][2]); pk.w = f2bf(acc[i][j][3]);
                *(ushort4*)(Vt + (size_t)b * 512 * 2048 + (size_t)d * 2048 + s0) = pk;
            }
    }
}

// scores: P[b][q][kv] = exp(G . X) causal-masked, unnormalized, bf16.
// B-operand is Xb itself (K projection eliminated algebraically).
__global__ __launch_bounds__(256, 4) void k_scores(const u16* __restrict__ Gb, const u16* __restrict__ Xb,
                                                   u16* __restrict__ P) {
    const int bid = blockIdx.x;
    const int bz = bid & 7;
    const int tt = bid >> 3;  // 0..135
    int qi = (int)((sqrtf(8.0f * tt + 1.0f) - 1.0f) * 0.5f);
    while ((qi + 1) * (qi + 2) / 2 <= tt) ++qi;
    while (qi * (qi + 1) / 2 > tt) --qi;
    const int kvj = tt - qi * (qi + 1) / 2;  // 0..qi

    __shared__ alignas(16) u16 Alds[8192];
    __shared__ alignas(16) u16 Blds[8192];
    const u16* Ag = Gb + (size_t)bz * 2048 * 512 + (size_t)qi * 128 * 512;
    const u16* Bg = Xb + (size_t)bz * 2048 * 512 + (size_t)kvj * 128 * 512;
    skew(bid);
    f32x4 acc[4][4] = {};
    gemm64<4, false>(Ag, 512, Bg, 512, 8, Alds, Blds, acc, (f32x4*)nullptr);

    const int t = threadIdx.x, lane = t & 63, w = t >> 6;
    const int wr = (w >> 1) * 64, wc = (w & 1) * 64;
    u16* Pb = P + (size_t)bz * 2048 * 2048;
#pragma unroll
    for (int i = 0; i < 4; ++i)
#pragma unroll
        for (int j = 0; j < 4; ++j)
#pragma unroll
            for (int r = 0; r < 4; ++r) {
                int q = qi * 128 + wr + i * 16 + 4 * (lane >> 4) + r;
                int kv = kvj * 128 + wc + j * 16 + (lane & 15);
                float pv = (kv <= q) ? __expf(acc[i][j][r]) : 0.0f;
                Pb[(size_t)q * 2048 + kv] = f2bf(pv);
            }
}

// PV: out = (P @ Vt) / rowsum(P); rowsum via ones-MFMA. BK=64, 24KB LDS.
// 1024 blocks; bz = bid&7 (XCD/batch affinity); quarter mapping keeps per-CU
// work constant (pairs qi2 and 31-qi2).
__global__ __launch_bounds__(256, 4) void k_pv(const u16* __restrict__ P, const u16* __restrict__ Vt,
                                               float* __restrict__ Out) {
    __shared__ alignas(16) u16 Alds[4096];   // 64q x 64kv
    __shared__ alignas(16) u16 Blds[8192];   // 128d x 64kv
    const int bid = blockIdx.x;
    const int bz = bid & 7;
    const int u = bid >> 3;        // 0..127
    const int g = u >> 5;          // quarter = nt
    const int s = u & 31;
    const int nt = g;
    const int qi2 = (g & 1) ? (31 - s) : s;   // 64-row q tile
    const int ksteps = qi2 + 1;               // causal extent in 64-wide kv tiles

    const u16* Ag = P + (size_t)bz * 2048 * 2048 + (size_t)qi2 * 64 * 2048;
    const u16* Bg = Vt + (size_t)bz * 512 * 2048 + (size_t)nt * 128 * 2048;
    skew(bid);
    f32x4 acc[2][4] = {};
    f32x4 accL[2] = {};
    gemm64<2, true>(Ag, 2048, Bg, 2048, ksteps, Alds, Blds, acc, accL);

    const int t = threadIdx.x, lane = t & 63, w = t >> 6;
    const int l = lane & 15, g4 = lane >> 4;
    const int wr = (w >> 1) * 32, wc = (w & 1) * 64;
#pragma unroll
    for (int i = 0; i < 2; ++i) {
        float inv[4];
#pragma unroll
        for (int r = 0; r < 4; ++r) inv[r] = 1.0f / accL[i][r];
#pragma unroll
        for (int j = 0; j < 4; ++j) {
            const int d = nt * 128 + wc + j * 16 + l;
#pragma unroll
            for (int r = 0; r < 4; ++r) {
                const int q = qi2 * 64 + wr + i * 16 + 4 * g4 + r;
                Out[(size_t)bz * 2048 * 512 + (size_t)q * 512 + d] = acc[i][j][r] * inv[r];
            }
        }
    }
}

// ---------------- launch ----------------

extern "C" void kernel_launch(void* const* d_in, const int* in_sizes, int n_in,
                              void* d_out, int out_size, void* d_ws, size_t ws_size,
                              hipStream_t stream) {
    const float* data = (const float*)d_in[0];
    const float* Wq = (const float*)d_in[1];
    const float* Wk = (const float*)d_in[2];
    const float* Wv = (const float*)d_in[3];
    float* out = (float*)d_out;
    char* ws = (char*)d_ws;

    // workspace layout (bytes)
    u16* Xb = (u16*)(ws);                 // 16 MB  [16384][512] bf16 data
    u16* Gb = (u16*)(ws + 16777216);      // 16 MB  G = X*M (replaces Q)
    u16* Mt = (u16*)(ws + 33554432);      // 512 KB [n'][k'] bf16 = M^T, scaled
    u16* Vt = (u16*)(ws + 50331648);      // 16 MB  V^T [b][d][s]
    u16* Wt = (u16*)(ws + 67108864);      // 1.5 MB bf16 {Wq native, Wk native, Wv^T}
    u16* P  = (u16*)(ws + 68681728);      // 64 MB  [b][q][kv] bf16 exp(scores)

    k_cvt<<<2816, 256, 0, stream>>>((const float4*)data, (ushort4*)Xb, Wq, Wk, Wv, Wt);
    k_gemm_m<<<16, 256, 0, stream>>>(Wt, Mt);
    k_proj<<<1024, 256, 0, stream>>>(Xb, Wt, Mt, Gb, Vt);
    k_scores<<<1088, 256, 0, stream>>>(Gb, Xb, P);
    k_pv<<<1024, 256, 0, stream>>>(P, Vt, out);
}